// Round 1
// 340.383 us; speedup vs baseline: 1.0968x; 1.0968x over previous
//
#include <hip/hip_runtime.h>
#include <math.h>

#define DM    1024
#define NH    16
#define HD    64
#define SEQ   2048
#define BATCH 4
#define TOKENS (BATCH * SEQ)     // 8192

typedef _Float16 half2v __attribute__((ext_vector_type(2)));
typedef __fp16   fp16x2 __attribute__((ext_vector_type(2)));
typedef _Float16 half4  __attribute__((ext_vector_type(4)));
typedef _Float16 half8  __attribute__((ext_vector_type(8)));
typedef float    f32x4  __attribute__((ext_vector_type(4)));
typedef float    f32x16 __attribute__((ext_vector_type(16)));
typedef unsigned int u32x2 __attribute__((ext_vector_type(2)));
typedef unsigned int u32x4 __attribute__((ext_vector_type(4)));

typedef const __attribute__((address_space(1))) void* gas_p;
typedef __attribute__((address_space(3))) void*       las_p;

__device__ __forceinline__ void gload_lds16(const void* g, void* l) {
    __builtin_amdgcn_global_load_lds((gas_p)g, (las_p)l, 16, 0, 0);
}

__device__ __forceinline__ unsigned pack2u(float a, float b) {
    fp16x2 r = __builtin_amdgcn_cvt_pkrtz(a, b);
    return __builtin_bit_cast(unsigned, r);
}

#define MFMA16(a, b, c) __builtin_amdgcn_mfma_f32_16x16x32_f16((a), (b), (c), 0, 0, 0)
#define MFMA32(a, b, c) __builtin_amdgcn_mfma_f32_32x32x16_f16((a), (b), (c), 0, 0, 0)

// ---------------------------------------------------------------------------
// One fused fp32->fp16 convert over all 7 tensors (dst regions contiguous).
// ---------------------------------------------------------------------------
__global__ __launch_bounds__(256) void cvt_all(
    const float* __restrict__ q, const float* __restrict__ k,
    const float* __restrict__ v, const float* __restrict__ wq,
    const float* __restrict__ wk, const float* __restrict__ wv,
    const float* __restrict__ wo, _Float16* __restrict__ dst)
{
    const size_t TD = (size_t)TOKENS * DM, WD = (size_t)DM * DM;
    const size_t i = ((size_t)blockIdx.x * 256 + threadIdx.x) * 4;
    const float* s; size_t off;
    if      (i <     TD)          { s = q;  off = i; }
    else if (i < 2 * TD)          { s = k;  off = i - TD; }
    else if (i < 3 * TD)          { s = v;  off = i - 2 * TD; }
    else if (i < 3 * TD + WD)     { s = wq; off = i - 3 * TD; }
    else if (i < 3 * TD + 2 * WD) { s = wk; off = i - 3 * TD - WD; }
    else if (i < 3 * TD + 3 * WD) { s = wv; off = i - 3 * TD - 2 * WD; }
    else                          { s = wo; off = i - 3 * TD - 3 * WD; }
    const float4 x = *(const float4*)(s + off);
    half4 h = { (_Float16)x.x, (_Float16)x.y, (_Float16)x.z, (_Float16)x.w };
    *(half4*)(dst + i) = h;
}

// ---------------------------------------------------------------------------
// Fused QKV projection: grid (64, 8, 3); z selects A/W/bias/C and store mode.
// z 0,1: per-head [B,H,S,hd] fp16 (z0 scaled by log2(e)/8); z 2: [B,H,hd,S].
// ---------------------------------------------------------------------------
__global__ __launch_bounds__(256) void qkv_gemm(
    const _Float16* __restrict__ Abase, const _Float16* __restrict__ Wbase,
    const float* __restrict__ bq, const float* __restrict__ bk,
    const float* __restrict__ bv, _Float16* __restrict__ Cbase, float qscale)
{
    __shared__ __align__(16) _Float16 As[128 * 32];
    __shared__ __align__(16) _Float16 Ws[128 * 32];

    const int z = blockIdx.z;
    const size_t TD = (size_t)TOKENS * DM, WD = (size_t)DM * DM;
    const _Float16* A = Abase + (size_t)z * TD;
    const _Float16* W = Wbase + (size_t)z * WD;
    const float* bias = (z == 0) ? bq : (z == 1) ? bk : bv;
    _Float16* C = Cbase + (size_t)z * TD;
    const float scale = (z == 0) ? qscale : 1.0f;

    const int t = threadIdx.x;
    const int w = t >> 6, l = t & 63;
    const int tx = l & 15, quad = l >> 4;
    const int m0 = blockIdx.x * 128, n0 = blockIdx.y * 128;
    const int wm = (w & 1) * 64, wn = (w >> 1) * 64;
    const int srow = t >> 2, schk = t & 3;

    const _Float16* Ag = A + (size_t)m0 * DM;
    const _Float16* Wg = W + (size_t)n0 * DM;

    f32x4 acc[4][4] = {};

    for (int k0 = 0; k0 < DM; k0 += 32) {
        __syncthreads();
        #pragma unroll
        for (int i = 0; i < 2; ++i) {
            gload_lds16(Ag + (size_t)(i * 64 + srow) * DM + k0 + schk * 8,
                        As + (size_t)(i * 256 + (t & ~63)) * 8);
            gload_lds16(Wg + (size_t)(i * 64 + srow) * DM + k0 + schk * 8,
                        Ws + (size_t)(i * 256 + (t & ~63)) * 8);
        }
        __syncthreads();

        half8 af[4], bf[4];
        #pragma unroll
        for (int mt = 0; mt < 4; ++mt)
            af[mt] = *(const half8*)(As + (wm + mt * 16 + tx) * 32 + quad * 8);
        #pragma unroll
        for (int nt = 0; nt < 4; ++nt)
            bf[nt] = *(const half8*)(Ws + (wn + nt * 16 + tx) * 32 + quad * 8);
        #pragma unroll
        for (int mt = 0; mt < 4; ++mt)
            #pragma unroll
            for (int nt = 0; nt < 4; ++nt)
                acc[mt][nt] = MFMA16(af[mt], bf[nt], acc[mt][nt]);
    }

    float bsv[4];
    #pragma unroll
    for (int nt = 0; nt < 4; ++nt) bsv[nt] = bias[n0 + wn + nt * 16 + tx];

    #pragma unroll
    for (int mt = 0; mt < 4; ++mt) {
        #pragma unroll
        for (int nt = 0; nt < 4; ++nt) {
            const int n = n0 + wn + nt * 16 + tx;
            const int mr0 = m0 + wm + mt * 16 + quad * 4;
            const int h = n >> 6, d = n & 63;
            if (z < 2) {
                #pragma unroll
                for (int r = 0; r < 4; ++r) {
                    const int m = mr0 + r;
                    const int b = m >> 11, s = m & (SEQ - 1);
                    const float vv = (acc[mt][nt][r] + bsv[nt]) * scale;
                    C[(((size_t)b * NH + h) * SEQ + s) * HD + d] = (_Float16)vv;
                }
            } else {
                const int b = mr0 >> 11, s0 = mr0 & (SEQ - 1);
                half4 hv = { (_Float16)(acc[mt][nt][0] + bsv[nt]),
                             (_Float16)(acc[mt][nt][1] + bsv[nt]),
                             (_Float16)(acc[mt][nt][2] + bsv[nt]),
                             (_Float16)(acc[mt][nt][3] + bsv[nt]) };
                *(half4*)(C + (((size_t)b * NH + h) * HD + d) * SEQ + s0) = hv;
            }
        }
    }
}

// ---------------------------------------------------------------------------
// Output projection GEMM: C fp32 [m,n] = A[m,k] W[n,k] + bias.
// ---------------------------------------------------------------------------
__global__ __launch_bounds__(256) void out_gemm(
    const _Float16* __restrict__ A, const _Float16* __restrict__ W,
    const float* __restrict__ bias, float* __restrict__ C)
{
    __shared__ __align__(16) _Float16 As[128 * 32];
    __shared__ __align__(16) _Float16 Ws[128 * 32];

    const int t = threadIdx.x;
    const int w = t >> 6, l = t & 63;
    const int tx = l & 15, quad = l >> 4;
    const int m0 = blockIdx.x * 128, n0 = blockIdx.y * 128;
    const int wm = (w & 1) * 64, wn = (w >> 1) * 64;
    const int srow = t >> 2, schk = t & 3;

    const _Float16* Ag = A + (size_t)m0 * DM;
    const _Float16* Wg = W + (size_t)n0 * DM;

    f32x4 acc[4][4] = {};

    for (int k0 = 0; k0 < DM; k0 += 32) {
        __syncthreads();
        #pragma unroll
        for (int i = 0; i < 2; ++i) {
            gload_lds16(Ag + (size_t)(i * 64 + srow) * DM + k0 + schk * 8,
                        As + (size_t)(i * 256 + (t & ~63)) * 8);
            gload_lds16(Wg + (size_t)(i * 64 + srow) * DM + k0 + schk * 8,
                        Ws + (size_t)(i * 256 + (t & ~63)) * 8);
        }
        __syncthreads();

        half8 af[4], bf[4];
        #pragma unroll
        for (int mt = 0; mt < 4; ++mt)
            af[mt] = *(const half8*)(As + (wm + mt * 16 + tx) * 32 + quad * 8);
        #pragma unroll
        for (int nt = 0; nt < 4; ++nt)
            bf[nt] = *(const half8*)(Ws + (wn + nt * 16 + tx) * 32 + quad * 8);
        #pragma unroll
        for (int mt = 0; mt < 4; ++mt)
            #pragma unroll
            for (int nt = 0; nt < 4; ++nt)
                acc[mt][nt] = MFMA16(af[mt], bf[nt], acc[mt][nt]);
    }

    float bsv[4];
    #pragma unroll
    for (int nt = 0; nt < 4; ++nt) bsv[nt] = bias[n0 + wn + nt * 16 + tx];

    #pragma unroll
    for (int mt = 0; mt < 4; ++mt)
        #pragma unroll
        for (int nt = 0; nt < 4; ++nt) {
            const int n = n0 + wn + nt * 16 + tx;
            const int mr0 = m0 + wm + mt * 16 + quad * 4;
            #pragma unroll
            for (int r = 0; r < 4; ++r)
                C[(size_t)(mr0 + r) * DM + n] = acc[mt][nt][r] + bsv[nt];
        }
}

// ---------------------------------------------------------------------------
// Flash attention v4 — 32x32 MFMA + fully in-register softmax (T12).
// grid 1024 (XCD-bijective decode: all 16 q-tiles of one (b,h) on one XCD),
// block 256 = 4 waves; wave w owns q rows w*32..w*32+31 (split-Q, l deferred).
// K-tile 64 keys, double-buffered LDS via global_load_lds with XOR-swizzled
// global source (chunk ^ (row&7)); fragment reads apply the same involution
// -> conflict-free b128.
// S^T = mfma_32x32x16(K, Q): lane holds q = lane&31, keys (reg&3)+8*(reg>>2)
// +4*(lane>>5). P = exp2(S) packed via cvt_pkrtz; PV A-fragments built
// IN-REGISTER with permlane32_swap (r0 = {x.lo, y.lo} = dw0, r1 = {x.hi,
// y.hi} = dw2) — no P LDS round trip, no lgkm stall between MFMA clusters.
// Per wave per tile: 8 S-MFMA + 32 exp2 + 16 cvt_pk + 8 permlane + 8 PV-MFMA.
// LDS 35 KB (was 51.7); s_setprio(1) around MFMA clusters.
// ---------------------------------------------------------------------------
__global__ __launch_bounds__(256, 3) void flash16(
    const _Float16* __restrict__ Q, const _Float16* __restrict__ K,
    const _Float16* __restrict__ Vt, _Float16* __restrict__ AO)
{
    // pool: Kst[2][8KB] | Vst[2][8KB] = 32768 B
    // epilogue aliases pool as float Obuf[128][68] (34816 B)
    __shared__ __align__(16) char pool[34816];
    __shared__ float lW[128];

    const int t = threadIdx.x, w = t >> 6, l = t & 63;
    const int lid = l & 31, hl = l >> 5;

    // XCD-bijective block swizzle: bid%8 selects XCD (assumed round-robin);
    // each XCD gets 8 consecutive bh groups -> K/V L2-resident per XCD.
    const int bid = blockIdx.x;
    const int xcd = bid & 7, loc = bid >> 3;
    const int bh = xcd * 8 + (loc >> 4);
    const int q0 = (loc & 15) * 128;
    const int b = bh >> 4, h = bh & 15;

    const _Float16* Qg = Q + ((size_t)bh * SEQ + q0 + w * 32) * HD;
    const _Float16* Kg = K + (size_t)bh * SEQ * HD;
    const _Float16* Vg = Vt + (size_t)bh * HD * SEQ;

    // staging source swizzle (per lane, constant across iters)
    const int srow = l >> 3;             // 0..7 row within 8-row instr group
    const int schk = (l & 7) ^ srow;     // swizzled 16B chunk within 128B row

    // Q B-fragments, in registers whole kernel: B[k=d][n=q], k = hl*8+j
    half8 Qf[4];
    #pragma unroll
    for (int ks = 0; ks < 4; ++ks)
        Qf[ks] = *(const half8*)(Qg + (size_t)lid * HD + ks * 16 + hl * 8);

    f32x16 Oa[2] = {};    // D[q][d]: d = dt*32+lid, q = (reg&3)+8*(reg>>2)+4*hl
    float l2 = 0.f;       // per-lane partial denom for q = lid
    const half2v one2 = { (_Float16)1.0f, (_Float16)1.0f };

    // ---- stage tile 0 into buffer 0 (wave w issues rows 8w.. and 8(w+4)..)
    {
        _Float16* KL = (_Float16*)(pool);
        _Float16* VL = (_Float16*)(pool + 16384);
        #pragma unroll
        for (int jj = 0; jj < 2; ++jj) {
            const int j = w + jj * 4;
            const int row = 8 * j + srow;
            gload_lds16(Kg + (size_t)row * HD + schk * 8, KL + j * 512);
            gload_lds16(Vg + (size_t)row * SEQ + schk * 8, VL + j * 512);
        }
    }

    for (int it = 0; it < SEQ / 64; ++it) {
        __syncthreads();   // vmcnt(0)+barrier: tile `it` staged, prev compute done

        // ---- issue next-tile staging into the other buffer (overlaps compute)
        if (it < SEQ / 64 - 1) {
            const int kb = (it + 1) * 64;
            _Float16* KL = (_Float16*)(pool + ((it + 1) & 1) * 8192);
            _Float16* VL = (_Float16*)(pool + 16384 + ((it + 1) & 1) * 8192);
            #pragma unroll
            for (int jj = 0; jj < 2; ++jj) {
                const int j = w + jj * 4;
                const int row = 8 * j + srow;
                gload_lds16(Kg + (size_t)(kb + row) * HD + schk * 8, KL + j * 512);
                gload_lds16(Vg + (size_t)row * SEQ + kb + schk * 8, VL + j * 512);
            }
        }

        const _Float16* KL = (const _Float16*)(pool + (it & 1) * 8192);
        const _Float16* VL = (const _Float16*)(pool + 16384 + (it & 1) * 8192);

        // ---- K A-fragments: A[m=key][k=d], key = kt*32+lid, d = ks*16+hl*8+j
        half8 kf[2][4];
        #pragma unroll
        for (int kt = 0; kt < 2; ++kt)
            #pragma unroll
            for (int ks = 0; ks < 4; ++ks)
                kf[kt][ks] = *(const half8*)(KL + (kt * 32 + lid) * 64 +
                                             (((ks * 2 + hl) ^ (lid & 7)) * 8));

        // ---- S^T = K.Q^T : D[key][q]
        f32x16 sacc[2];
        __builtin_amdgcn_s_setprio(1);
        #pragma unroll
        for (int kt = 0; kt < 2; ++kt) {
            f32x16 s = {};
            #pragma unroll
            for (int ks = 0; ks < 4; ++ks)
                s = MFMA32(kf[kt][ks], Qf[ks], s);
            sacc[kt] = s;
        }
        __builtin_amdgcn_s_setprio(0);

        // ---- V B-fragments: B[k=key][n=d], key = kstep*16+hl*8+j, d = dt*32+lid
        // (issued here so the reads overlap the softmax VALU chain)
        half8 vf[4][2];
        #pragma unroll
        for (int kstep = 0; kstep < 4; ++kstep)
            #pragma unroll
            for (int dt = 0; dt < 2; ++dt)
                vf[kstep][dt] = *(const half8*)(VL + (dt * 32 + lid) * 64 +
                                                (((kstep * 2 + hl) ^ (lid & 7)) * 8));

        // ---- P = exp2(S); l += sum; pack pairs of consecutive keys to fp16
        // cf[kt][g][s]: keys kt*32 + 8g + 4*hl + {2s, 2s+1}, q = lid
        unsigned cf[2][4][2];
        #pragma unroll
        for (int kt = 0; kt < 2; ++kt)
            #pragma unroll
            for (int g = 0; g < 4; ++g) {
                const float p0 = __builtin_amdgcn_exp2f(sacc[kt][g * 4 + 0]);
                const float p1 = __builtin_amdgcn_exp2f(sacc[kt][g * 4 + 1]);
                const float p2 = __builtin_amdgcn_exp2f(sacc[kt][g * 4 + 2]);
                const float p3 = __builtin_amdgcn_exp2f(sacc[kt][g * 4 + 3]);
                const unsigned ca = pack2u(p0, p1);
                const unsigned cb = pack2u(p2, p3);
                l2 = __builtin_amdgcn_fdot2(__builtin_bit_cast(half2v, ca), one2, l2, false);
                l2 = __builtin_amdgcn_fdot2(__builtin_bit_cast(half2v, cb), one2, l2, false);
                cf[kt][g][0] = ca;
                cf[kt][g][1] = cb;
            }

        // ---- PV with in-register transpose: per kstep (16 keys) build A-frag
        // A[m=q][k=key], key = kstep*16 + hl*8 + j via 2 permlane32_swap.
        __builtin_amdgcn_s_setprio(1);
        #pragma unroll
        for (int kstep = 0; kstep < 4; ++kstep) {
            const int kt = kstep >> 1, g0 = (kstep & 1) * 2;
            const u32x2 r0 = __builtin_amdgcn_permlane32_swap(
                cf[kt][g0][0], cf[kt][g0 + 1][0], false, false);
            const u32x2 r1 = __builtin_amdgcn_permlane32_swap(
                cf[kt][g0][1], cf[kt][g0 + 1][1], false, false);
            const u32x4 pw = { r0[0], r1[0], r0[1], r1[1] };
            const half8 pa = __builtin_bit_cast(half8, pw);
            #pragma unroll
            for (int dt = 0; dt < 2; ++dt)
                Oa[dt] = MFMA32(pa, vf[kstep][dt], Oa[dt]);
        }
        __builtin_amdgcn_s_setprio(0);
    }

    // ---- deferred denominator: reduce over lane halves, publish
    l2 += __shfl_xor(l2, 32, 64);
    if (l < 32) lW[w * 32 + l] = l2;
    __syncthreads();   // all LDS reads done -> safe to alias pool as Obuf

    // ---- O (C-layout regs) -> Obuf [128][68] fp32
    float* Ob = (float*)pool;
    #pragma unroll
    for (int dt = 0; dt < 2; ++dt)
        #pragma unroll
        for (int g = 0; g < 4; ++g)
            #pragma unroll
            for (int r = 0; r < 4; ++r)
                Ob[(w * 32 + g * 8 + hl * 4 + r) * 68 + dt * 32 + lid] = Oa[dt][g * 4 + r];
    __syncthreads();

    // ---- normalize + store AO [token][1024] fp16 (16B stores)
    {
        const int row = t >> 1, cb = (t & 1) * 32;
        const float inv = 1.0f / lW[row];
        _Float16* dst = AO + ((size_t)b * SEQ + q0 + row) * DM + h * HD + cb;
        #pragma unroll
        for (int j = 0; j < 32; j += 8) {
            const f32x4 o0 = *(const f32x4*)(Ob + row * 68 + cb + j);
            const f32x4 o1 = *(const f32x4*)(Ob + row * 68 + cb + j + 4);
            half8 hv = { (_Float16)(o0[0] * inv), (_Float16)(o0[1] * inv),
                         (_Float16)(o0[2] * inv), (_Float16)(o0[3] * inv),
                         (_Float16)(o1[0] * inv), (_Float16)(o1[1] * inv),
                         (_Float16)(o1[2] * inv), (_Float16)(o1[3] * inv) };
            *(half8*)(dst + j) = hv;
        }
    }
}

// ---------------------------------------------------------------------------
extern "C" void kernel_launch(void* const* d_in, const int* in_sizes, int n_in,
                              void* d_out, int out_size, void* d_ws, size_t ws_size,
                              hipStream_t stream)
{
    const float* q  = (const float*)d_in[0];
    const float* k  = (const float*)d_in[1];
    const float* v  = (const float*)d_in[2];
    const float* Wq = (const float*)d_in[3];
    const float* bq = (const float*)d_in[4];
    const float* Wk = (const float*)d_in[5];
    const float* bk = (const float*)d_in[6];
    const float* Wv = (const float*)d_in[7];
    const float* bv = (const float*)d_in[8];
    const float* Wo = (const float*)d_in[9];
    const float* bo = (const float*)d_in[10];
    float* out = (float*)d_out;

    const size_t TD = (size_t)TOKENS * DM;     // 8.39M
    const size_t WD = (size_t)DM * DM;         // 1.05M
    _Float16* ws = (_Float16*)d_ws;
    _Float16* cvtbase = ws;                    // q16|k16|v16|wq16|wk16|wv16|wo16
    _Float16* q16  = ws;
    _Float16* wq16 = ws + 3 * TD;
    _Float16* wo16 = wq16 + 3 * WD;
    _Float16* Qw   = ws + 3 * TD + 4 * WD;     // Qw|Kw|Vtw contiguous
    _Float16* Kw   = Qw + TD;
    _Float16* Vtw  = Kw + TD;
    _Float16* AOw  = Vtw + TD;

    const int gC = (int)((3 * TD + 4 * WD) / 4 / 256);   // 28672
    cvt_all<<<gC, 256, 0, stream>>>(q, k, v, Wq, Wk, Wv, Wo, cvtbase);

    const float qscale = 0.18033688011112042f; // log2(e)/sqrt(64)
    qkv_gemm<<<dim3(TOKENS / 128, DM / 128, 3), 256, 0, stream>>>(
        q16, wq16, bq, bk, bv, Qw, qscale);

    flash16<<<dim3((SEQ / 128) * BATCH * NH), 256, 0, stream>>>(Qw, Kw, Vtw, AOw);

    out_gemm<<<dim3(TOKENS / 128, DM / 128, 1), 256, 0, stream>>>(AOw, wo16, bo, out);
}